// Round 1
// baseline (368.940 us; speedup 1.0000x reference)
//
#include <hip/hip_runtime.h>
#include <hip/hip_bf16.h>
#include <stdint.h>

typedef short short8 __attribute__((ext_vector_type(8)));
typedef float f32x4 __attribute__((ext_vector_type(4)));

#define PXS 40     // padded LDS row stride (elements) — balanced bank-quad spread

__device__ __forceinline__ short f2bf(float f) {
    __hip_bfloat16 h = __float2bfloat16(f);
    return __builtin_bit_cast(short, h);
}

// ---- prep 1a: K2(ci,co) = sum_p kernel[p,ci,co]^2  (256 blocks) ------------
__global__ void prep_k2(const float* __restrict__ kern, float* __restrict__ K2)
{
    const int ci = blockIdx.x, co = threadIdx.x;
    float acc = 0.f;
#pragma unroll
    for (int p = 0; p < 9; ++p) {
        float w = kern[(p * 256 + ci) * 256 + co];
        acc += w * w;
    }
    K2[ci * 256 + co] = acc;
}

// ---- prep 1b: demod(b,co) = 1/sqrt( sum_ci style^2 * K2 + eps ) ------------
__global__ void prep_demod(const float* __restrict__ style,
                           const float* __restrict__ K2,
                           float* __restrict__ demod)
{
    const int b = blockIdx.x, co = threadIdx.x;
    __shared__ float s2[256];
    float s = style[b * 256 + co];
    s2[co] = s * s;
    __syncthreads();
    float acc = 0.f;
#pragma unroll 8
    for (int ci = 0; ci < 256; ++ci)
        acc += s2[ci] * K2[ci * 256 + co];
    demod[b * 256 + co] = 1.0f / sqrtf(acc + 1e-7f);
}

// ---- prep 2: fragment-major bf16 weights ----------------------------------
// KF chunk layout: [(st = sl*3+tp)][jt][lane] of short8 (16 B per lane).
// Lane (l15 = lane&15, lk = lane>>4) holds B[n = jt*16+l15][k = lk*8+e] for
// slice sl = dh*8+cc (ci = cc*32 + k), tap tp (p = dh*3+tp).
// One wave's MFMA B-fragment = one contiguous 1024 B chunk -> a single
// perfectly-coalesced global_load per (tap, j-tile) in the conv kernel.
__global__ void prep_kf(const float* __restrict__ kern,
                        __hip_bfloat16* __restrict__ kf)
{
    const int st = blockIdx.x;                 // 0..71
    const int sl = st / 3, tp = st - sl * 3;
    const int dh = sl >> 3, cc = sl & 7;
    const int p  = dh * 3 + tp;
    const int t    = threadIdx.x;
    const int lane = t & 63, jt2 = t >> 6;
    const int l15  = lane & 15, lk = lane >> 4;
    const int cib  = cc * 32 + lk * 8;
#pragma unroll
    for (int jj = 0; jj < 4; ++jj) {
        const int jt = jj * 4 + jt2;
        const int co = jt * 16 + l15;
        short8 v;
#pragma unroll
        for (int e = 0; e < 8; ++e)
            v[e] = f2bf(kern[(size_t)(p * 256 + cib + e) * 256 + co]);
        *(short8*)(kf + ((size_t)(st * 16 + jt) * 64 + lane) * 8) = v;
    }
}

// ---- main: implicit-GEMM conv, f32 in / f32 out, bf16 MFMA core ------------
// One block = one (b,h) row (M=128 pixels) x 128 couts.
// v2 changes vs previous session:
//  * B operand: direct per-lane global loads from fragment-major KF (L1/L2
//    resident, 1.18 MB total) — Bs LDS staging removed entirely. Cuts LDS
//    wave-ops per slice ~2x (was the ~68%-busy pipe per conflict-counter math).
//  * Xs double-buffered (2 x 10.4 KB) + T14 async-stage split: next slice's
//    x loads issued BEFORE the MFMA phase, modulate+ds_write after, ONE
//    __syncthreads per slice (was 2 full drains).
//  * slice skip (h edge) expressed as contiguous range [slo,shi) so the
//    pipeline stays uniform.
__global__ __launch_bounds__(256) void conv_mfma(
    const float* __restrict__ x,
    const __hip_bfloat16* __restrict__ kf,
    const float* __restrict__ style,
    const float* __restrict__ demod,
    float* __restrict__ out)
{
    __shared__ __align__(16) __hip_bfloat16 Xs[2][130 * PXS];   // 20.8 KB
    __shared__ float Ss[256];
    __shared__ float Ds[128];

    const int t    = threadIdx.x;
    const int bid  = blockIdx.x;
    const int L    = ((bid & 7) << 8) | (bid >> 3);   // XCD-contiguous work id
    const int n0   = (L & 1) << 7;                    // cout tile: 0 or 128
    const int bh   = L >> 1;                          // 0..1023
    const int b    = bh >> 7, h = bh & 127;
    const int wave = t >> 6, lane = t & 63;
    const int wr   = (wave >> 1) << 6;          // wave row base
    const int wc   = (wave & 1) << 6;           // wave col base
    const int l15  = lane & 15, lk = lane >> 4;
    const int mA   = t >> 2;                    // staging row 0..63
    const int koff = (t & 3) << 3;              // staging k offset (8 elems)
    const int jbase = ((L & 1) << 3) + (wc >> 4);   // KF j-tile base for wave

    if (t < 128) {
        ((float2*)Ss)[t] = ((const float2*)(style + b * 256))[t];
        Ds[t] = demod[b * 256 + n0 + t];
    }
    if (t < 32) {                               // halo rows, never re-written
        const __hip_bfloat16 z = __float2bfloat16(0.f);
        Xs[0][t] = z; Xs[0][129 * PXS + t] = z;
        Xs[1][t] = z; Xs[1][129 * PXS + t] = z;
    }

    f32x4 acc[4][4] = {};

    const int slo = (h == 0)   ? 8  : 0;        // valid slices are contiguous
    const int shi = (h == 127) ? 16 : 24;

    __syncthreads();                            // Ss ready for staging

    // ---- prologue: stage slice slo into buffer 0 ----
    {
        const int h2  = h + (slo >> 3) - 1;
        const int ci0 = (slo & 7) << 5;
        const size_t rowbase = (size_t)(b * 128 + h2) * 128;
        const float* ga = x + (rowbase + mA)      * 256 + ci0 + koff;
        const float* gb = x + (rowbase + mA + 64) * 256 + ci0 + koff;
        float4 xa0 = *(const float4*)ga, xa1 = *(const float4*)(ga + 4);
        float4 xb0 = *(const float4*)gb, xb1 = *(const float4*)(gb + 4);
        float4 s0  = *(const float4*)&Ss[ci0 + koff];
        float4 s1  = *(const float4*)&Ss[ci0 + koff + 4];
        short8 ma, mb;
#pragma unroll
        for (int jj = 0; jj < 4; ++jj) {
            ma[jj]     = f2bf((&xa0.x)[jj] * (&s0.x)[jj]);
            ma[jj + 4] = f2bf((&xa1.x)[jj] * (&s1.x)[jj]);
            mb[jj]     = f2bf((&xb0.x)[jj] * (&s0.x)[jj]);
            mb[jj + 4] = f2bf((&xb1.x)[jj] * (&s1.x)[jj]);
        }
        *(short8*)&Xs[0][(mA + 1)  * PXS + koff] = ma;
        *(short8*)&Xs[0][(mA + 65) * PXS + koff] = mb;
    }
    __syncthreads();                            // buf0 published

    int cur = 0;
    for (int s = slo; s < shi; ++s, cur ^= 1) {
        // ---- T14 stage-split: issue next slice's x loads NOW ----
        float4 xa0, xa1, xb0, xb1;
        int nci0 = 0;
        const bool pf = (s + 1 < shi);
        if (pf) {
            const int sl = s + 1;
            const int h2 = h + (sl >> 3) - 1;
            nci0 = (sl & 7) << 5;
            const size_t rowbase = (size_t)(b * 128 + h2) * 128;
            const float* ga = x + (rowbase + mA)      * 256 + nci0 + koff;
            const float* gb = x + (rowbase + mA + 64) * 256 + nci0 + koff;
            xa0 = *(const float4*)ga; xa1 = *(const float4*)(ga + 4);
            xb0 = *(const float4*)gb; xb1 = *(const float4*)(gb + 4);
        }

        // ---- compute current slice: 3 taps x 4x4 tiles ----
        const size_t stbase = (size_t)s * 3 * 16;
#pragma unroll
        for (int tp = 0; tp < 3; ++tp) {        // dw=tp-1; pixel m reads row m+tp
            short8 bfr[4], af[4];
#pragma unroll
            for (int j = 0; j < 4; ++j)         // one coalesced 1 KB load each
                bfr[j] = *(const short8*)(kf +
                    (((stbase + tp * 16) + jbase + j) * 64 + lane) * 8);
#pragma unroll
            for (int i = 0; i < 4; ++i)
                af[i] = *(const short8*)&Xs[cur][(wr + i * 16 + l15 + tp) * PXS + lk * 8];
#pragma unroll
            for (int i = 0; i < 4; ++i)
#pragma unroll
                for (int j = 0; j < 4; ++j)
                    acc[i][j] = __builtin_amdgcn_mfma_f32_16x16x32_bf16(
                        af[i], bfr[j], acc[i][j], 0, 0, 0);
        }

        // ---- modulate + write next buffer (loads landed under the MFMAs) ----
        if (pf) {
            float4 s0 = *(const float4*)&Ss[nci0 + koff];
            float4 s1 = *(const float4*)&Ss[nci0 + koff + 4];
            short8 ma, mb;
#pragma unroll
            for (int jj = 0; jj < 4; ++jj) {
                ma[jj]     = f2bf((&xa0.x)[jj] * (&s0.x)[jj]);
                ma[jj + 4] = f2bf((&xa1.x)[jj] * (&s1.x)[jj]);
                mb[jj]     = f2bf((&xb0.x)[jj] * (&s0.x)[jj]);
                mb[jj + 4] = f2bf((&xb1.x)[jj] * (&s1.x)[jj]);
            }
            *(short8*)&Xs[cur ^ 1][(mA + 1)  * PXS + koff] = ma;
            *(short8*)&Xs[cur ^ 1][(mA + 65) * PXS + koff] = mb;
        }
        __syncthreads();                        // publishes buf^1, guards reuse
    }

    // ---- epilogue: demod scale + f32 store (C/D: col=lane&15, row=(lane>>4)*4+r)
    float dj[4];
#pragma unroll
    for (int j = 0; j < 4; ++j) dj[j] = Ds[wc + j * 16 + l15];
    const size_t obase = (size_t)(b * 128 + h) * 128 * 256 + n0;
#pragma unroll
    for (int i = 0; i < 4; ++i) {
#pragma unroll
        for (int j = 0; j < 4; ++j) {
            const int n = wc + j * 16 + l15;
#pragma unroll
            for (int r = 0; r < 4; ++r) {
                const int m = wr + i * 16 + lk * 4 + r;
                out[obase + (size_t)m * 256 + n] = acc[i][j][r] * dj[j];
            }
        }
    }
}

extern "C" void kernel_launch(void* const* d_in, const int* in_sizes, int n_in,
                              void* d_out, int out_size, void* d_ws, size_t ws_size,
                              hipStream_t stream)
{
    const float* x     = (const float*)d_in[0];
    const float* style = (const float*)d_in[1];
    const float* kern  = (const float*)d_in[2];
    float* out = (float*)d_out;

    char*  ws    = (char*)d_ws;
    float* demod = (float*)ws;                           // 2048 f32   (8 KB)
    float* K2    = (float*)(ws + 8192);                  // 65536 f32  (256 KB)
    __hip_bfloat16* kT = (__hip_bfloat16*)(ws + 270336); // 589824 bf16 (1.18 MB)

    prep_k2   <<<256, 256, 0, stream>>>(kern, K2);
    prep_demod<<<8,   256, 0, stream>>>(style, K2, demod);
    prep_kf   <<<72,  256, 0, stream>>>(kern, kT);
    conv_mfma <<<2048, 256, 0, stream>>>(x, kT, style, demod, out);
}

// Round 2
// 359.660 us; speedup vs baseline: 1.0258x; 1.0258x over previous
//
#include <hip/hip_runtime.h>
#include <hip/hip_bf16.h>
#include <stdint.h>

typedef short short8 __attribute__((ext_vector_type(8)));
typedef float f32x4 __attribute__((ext_vector_type(4)));

#define PXS 40     // padded LDS row stride (elements) — balanced bank-quad spread

__device__ __forceinline__ short f2bf(float f) {
    __hip_bfloat16 h = __float2bfloat16(f);
    return __builtin_bit_cast(short, h);
}

// ---- prep 1a: K2(ci,co) = sum_p kernel[p,ci,co]^2  (256 blocks) ------------
__global__ void prep_k2(const float* __restrict__ kern, float* __restrict__ K2)
{
    const int ci = blockIdx.x, co = threadIdx.x;
    float acc = 0.f;
#pragma unroll
    for (int p = 0; p < 9; ++p) {
        float w = kern[(p * 256 + ci) * 256 + co];
        acc += w * w;
    }
    K2[ci * 256 + co] = acc;
}

// ---- prep 1b: demod(b,co) = 1/sqrt( sum_ci style^2 * K2 + eps ) ------------
__global__ void prep_demod(const float* __restrict__ style,
                           const float* __restrict__ K2,
                           float* __restrict__ demod)
{
    const int b = blockIdx.x, co = threadIdx.x;
    __shared__ float s2[256];
    float s = style[b * 256 + co];
    s2[co] = s * s;
    __syncthreads();
    float acc = 0.f;
#pragma unroll 8
    for (int ci = 0; ci < 256; ++ci)
        acc += s2[ci] * K2[ci * 256 + co];
    demod[b * 256 + co] = 1.0f / sqrtf(acc + 1e-7f);
}

// ---- prep 2: fragment-major bf16 weights ----------------------------------
// KF chunk layout: [(st = sl*3+tp)][jt][lane] of short8 (16 B per lane).
// One wave's MFMA B-fragment = one contiguous 1024 B chunk -> a single
// perfectly-coalesced global_load per (tap, j-tile) in the conv kernel.
__global__ void prep_kf(const float* __restrict__ kern,
                        __hip_bfloat16* __restrict__ kf)
{
    const int st = blockIdx.x;                 // 0..71
    const int sl = st / 3, tp = st - sl * 3;
    const int dh = sl >> 3, cc = sl & 7;
    const int p  = dh * 3 + tp;
    const int t    = threadIdx.x;
    const int lane = t & 63, jt2 = t >> 6;
    const int l15  = lane & 15, lk = lane >> 4;
    const int cib  = cc * 32 + lk * 8;
#pragma unroll
    for (int jj = 0; jj < 4; ++jj) {
        const int jt = jj * 4 + jt2;
        const int co = jt * 16 + l15;
        short8 v;
#pragma unroll
        for (int e = 0; e < 8; ++e)
            v[e] = f2bf(kern[(size_t)(p * 256 + cib + e) * 256 + co]);
        *(short8*)(kf + ((size_t)(st * 16 + jt) * 64 + lane) * 8) = v;
    }
}

// ---- fragment load/compute helpers -----------------------------------------
__device__ __forceinline__ void load_tap(const __hip_bfloat16* __restrict__ kf,
                                         const __hip_bfloat16* __restrict__ Xrow,
                                         int sbase, int tp, int jbase, int lane,
                                         int wr, int l15, int lk,
                                         short8 af[4], short8 bfr[4])
{
#pragma unroll
    for (int j = 0; j < 4; ++j)
        bfr[j] = *(const short8*)(kf +
            (size_t)(sbase + tp * 16 + jbase + j) * 512 + lane * 8);
#pragma unroll
    for (int i = 0; i < 4; ++i)
        af[i] = *(const short8*)&Xrow[(wr + i * 16 + l15 + tp) * PXS + lk * 8];
}

__device__ __forceinline__ void mfma_tap(f32x4 acc[4][4],
                                         const short8 af[4], const short8 bfr[4])
{
#pragma unroll
    for (int i = 0; i < 4; ++i)
#pragma unroll
        for (int j = 0; j < 4; ++j)
            acc[i][j] = __builtin_amdgcn_mfma_f32_16x16x32_bf16(
                af[i], bfr[j], acc[i][j], 0, 0, 0);
}

// ---- main: implicit-GEMM conv, f32 in / f32 out, bf16 MFMA core ------------
// One block = one (b,h) row (M=128 pixels) x 128 couts.
// v3 changes vs v2:
//  * __launch_bounds__(256,3): v2's default bounds gave VGPR_Count=80 — with
//    a 64-VGPR accumulator that left 16 regs for ALL operands, so every
//    B-fragment global load was issued+waited just-in-time (serialized
//    ~200cyc L2 latency x24/slice -> MfmaUtil fell to 32%). Budget ~170 regs
//    (3 waves/SIMD = achieved occupancy anyway) so operands stay resident.
//  * Explicit tap ping-pong: load tap0+tap1 fragment sets up front, MFMA
//    tap0 while tap2 loads fly. x-prefetch issued AFTER tap0's loads so the
//    first MFMA's vmcnt wait covers only tap0, never the HBM x loads.
//  * Nontemporal epilogue stores (write-once output; keep L2 for x/kf).
__global__ __launch_bounds__(256, 3) void conv_mfma(
    const float* __restrict__ x,
    const __hip_bfloat16* __restrict__ kf,
    const float* __restrict__ style,
    const float* __restrict__ demod,
    float* __restrict__ out)
{
    __shared__ __align__(16) __hip_bfloat16 Xs[2][130 * PXS];   // 20.8 KB
    __shared__ float Ss[256];
    __shared__ float Ds[128];

    const int t    = threadIdx.x;
    const int bid  = blockIdx.x;
    const int L    = ((bid & 7) << 8) | (bid >> 3);   // XCD-contiguous work id
    const int n0   = (L & 1) << 7;                    // cout tile: 0 or 128
    const int bh   = L >> 1;                          // 0..1023
    const int b    = bh >> 7, h = bh & 127;
    const int wave = t >> 6, lane = t & 63;
    const int wr   = (wave >> 1) << 6;          // wave row base
    const int wc   = (wave & 1) << 6;           // wave col base
    const int l15  = lane & 15, lk = lane >> 4;
    const int mA   = t >> 2;                    // staging row 0..63
    const int koff = (t & 3) << 3;              // staging k offset (8 elems)
    const int jbase = ((L & 1) << 3) + ((wave & 1) << 2);  // KF j-tile base

    if (t < 128) {
        ((float2*)Ss)[t] = ((const float2*)(style + b * 256))[t];
        Ds[t] = demod[b * 256 + n0 + t];
    }
    if (t < 32) {                               // halo rows, never re-written
        const __hip_bfloat16 z = __float2bfloat16(0.f);
        Xs[0][t] = z; Xs[0][129 * PXS + t] = z;
        Xs[1][t] = z; Xs[1][129 * PXS + t] = z;
    }

    f32x4 acc[4][4] = {};

    const int slo = (h == 0)   ? 8  : 0;        // valid slices are contiguous
    const int shi = (h == 127) ? 16 : 24;

    __syncthreads();                            // Ss ready for staging

    // ---- prologue: stage slice slo into buffer 0 ----
    {
        const int h2  = h + (slo >> 3) - 1;
        const int ci0 = (slo & 7) << 5;
        const size_t rowbase = (size_t)(b * 128 + h2) * 128;
        const float* ga = x + (rowbase + mA)      * 256 + ci0 + koff;
        const float* gb = x + (rowbase + mA + 64) * 256 + ci0 + koff;
        float4 xa0 = *(const float4*)ga, xa1 = *(const float4*)(ga + 4);
        float4 xb0 = *(const float4*)gb, xb1 = *(const float4*)(gb + 4);
        float4 s0  = *(const float4*)&Ss[ci0 + koff];
        float4 s1  = *(const float4*)&Ss[ci0 + koff + 4];
        short8 ma, mb;
#pragma unroll
        for (int jj = 0; jj < 4; ++jj) {
            ma[jj]     = f2bf((&xa0.x)[jj] * (&s0.x)[jj]);
            ma[jj + 4] = f2bf((&xa1.x)[jj] * (&s1.x)[jj]);
            mb[jj]     = f2bf((&xb0.x)[jj] * (&s0.x)[jj]);
            mb[jj + 4] = f2bf((&xb1.x)[jj] * (&s1.x)[jj]);
        }
        *(short8*)&Xs[0][(mA + 1)  * PXS + koff] = ma;
        *(short8*)&Xs[0][(mA + 65) * PXS + koff] = mb;
    }
    __syncthreads();                            // buf0 published

    int cur = 0;
    for (int s = slo; s < shi; ++s, cur ^= 1) {
        const int sbase = s * 48;               // KF chunk base for this slice
        const __hip_bfloat16* Xr = Xs[cur];

        short8 afA[4], bfA[4], afB[4], bfB[4];
        // tap0 + tap1 operand sets first — first MFMA waits only on tap0.
        load_tap(kf, Xr, sbase, 0, jbase, lane, wr, l15, lk, afA, bfA);
        load_tap(kf, Xr, sbase, 1, jbase, lane, wr, l15, lk, afB, bfB);

        mfma_tap(acc, afA, bfA);                // tap0

        // tap2 loads fly under tap1's MFMAs; x-prefetch issued after so no
        // MFMA ever waits on the HBM x loads.
        load_tap(kf, Xr, sbase, 2, jbase, lane, wr, l15, lk, afA, bfA);

        float4 xa0, xa1, xb0, xb1;
        int nci0 = 0;
        const bool pf = (s + 1 < shi);
        if (pf) {
            const int sl = s + 1;
            const int h2 = h + (sl >> 3) - 1;
            nci0 = (sl & 7) << 5;
            const size_t rowbase = (size_t)(b * 128 + h2) * 128;
            const float* ga = x + (rowbase + mA)      * 256 + nci0 + koff;
            const float* gb = x + (rowbase + mA + 64) * 256 + nci0 + koff;
            xa0 = *(const float4*)ga; xa1 = *(const float4*)(ga + 4);
            xb0 = *(const float4*)gb; xb1 = *(const float4*)(gb + 4);
        }

        mfma_tap(acc, afB, bfB);                // tap1
        mfma_tap(acc, afA, bfA);                // tap2

        // ---- modulate + write next buffer (x loads landed under MFMAs) ----
        if (pf) {
            float4 s0 = *(const float4*)&Ss[nci0 + koff];
            float4 s1 = *(const float4*)&Ss[nci0 + koff + 4];
            short8 ma, mb;
#pragma unroll
            for (int jj = 0; jj < 4; ++jj) {
                ma[jj]     = f2bf((&xa0.x)[jj] * (&s0.x)[jj]);
                ma[jj + 4] = f2bf((&xa1.x)[jj] * (&s1.x)[jj]);
                mb[jj]     = f2bf((&xb0.x)[jj] * (&s0.x)[jj]);
                mb[jj + 4] = f2bf((&xb1.x)[jj] * (&s1.x)[jj]);
            }
            *(short8*)&Xs[cur ^ 1][(mA + 1)  * PXS + koff] = ma;
            *(short8*)&Xs[cur ^ 1][(mA + 65) * PXS + koff] = mb;
        }
        __syncthreads();                        // publishes buf^1, guards reuse
    }

    // ---- epilogue: demod scale + f32 store (C/D: col=lane&15, row=(lane>>4)*4+r)
    float dj[4];
#pragma unroll
    for (int j = 0; j < 4; ++j) dj[j] = Ds[wc + j * 16 + l15];
    const size_t obase = (size_t)(b * 128 + h) * 128 * 256 + n0;
#pragma unroll
    for (int i = 0; i < 4; ++i) {
#pragma unroll
        for (int j = 0; j < 4; ++j) {
            const int n = wc + j * 16 + l15;
#pragma unroll
            for (int r = 0; r < 4; ++r) {
                const int m = wr + i * 16 + lk * 4 + r;
                __builtin_nontemporal_store(acc[i][j][r] * dj[j],
                                            &out[obase + (size_t)m * 256 + n]);
            }
        }
    }
}

extern "C" void kernel_launch(void* const* d_in, const int* in_sizes, int n_in,
                              void* d_out, int out_size, void* d_ws, size_t ws_size,
                              hipStream_t stream)
{
    const float* x     = (const float*)d_in[0];
    const float* style = (const float*)d_in[1];
    const float* kern  = (const float*)d_in[2];
    float* out = (float*)d_out;

    char*  ws    = (char*)d_ws;
    float* demod = (float*)ws;                           // 2048 f32   (8 KB)
    float* K2    = (float*)(ws + 8192);                  // 65536 f32  (256 KB)
    __hip_bfloat16* kT = (__hip_bfloat16*)(ws + 270336); // 589824 bf16 (1.18 MB)

    prep_k2   <<<256, 256, 0, stream>>>(kern, K2);
    prep_demod<<<8,   256, 0, stream>>>(style, K2, demod);
    prep_kf   <<<72,  256, 0, stream>>>(kern, kT);
    conv_mfma <<<2048, 256, 0, stream>>>(x, kT, style, demod, out);
}

// Round 3
// 358.487 us; speedup vs baseline: 1.0292x; 1.0033x over previous
//
#include <hip/hip_runtime.h>
#include <hip/hip_bf16.h>
#include <stdint.h>

typedef short short8 __attribute__((ext_vector_type(8)));
typedef float f32x4 __attribute__((ext_vector_type(4)));

#define PXS 40     // padded LDS row stride (elements) — balanced bank-quad spread

__device__ __forceinline__ short f2bf(float f) {
    __hip_bfloat16 h = __float2bfloat16(f);
    return __builtin_bit_cast(short, h);
}

// ---- prep 1a: K2(ci,co) = sum_p kernel[p,ci,co]^2  (256 blocks) ------------
__global__ void prep_k2(const float* __restrict__ kern, float* __restrict__ K2)
{
    const int ci = blockIdx.x, co = threadIdx.x;
    float acc = 0.f;
#pragma unroll
    for (int p = 0; p < 9; ++p) {
        float w = kern[(p * 256 + ci) * 256 + co];
        acc += w * w;
    }
    K2[ci * 256 + co] = acc;
}

// ---- prep 1b: demod(b,co) = 1/sqrt( sum_ci style^2 * K2 + eps ) ------------
__global__ void prep_demod(const float* __restrict__ style,
                           const float* __restrict__ K2,
                           float* __restrict__ demod)
{
    const int b = blockIdx.x, co = threadIdx.x;
    __shared__ float s2[256];
    float s = style[b * 256 + co];
    s2[co] = s * s;
    __syncthreads();
    float acc = 0.f;
#pragma unroll 8
    for (int ci = 0; ci < 256; ++ci)
        acc += s2[ci] * K2[ci * 256 + co];
    demod[b * 256 + co] = 1.0f / sqrtf(acc + 1e-7f);
}

// ---- prep 2: fragment-major bf16 weights ----------------------------------
// KF chunk layout: [(st = sl*3+tp)][jt][lane] of short8 (16 B per lane).
// One wave's MFMA B-fragment = one contiguous 1024 B chunk -> a single
// perfectly-coalesced global_load per (tap, j-tile) in the conv kernel.
__global__ void prep_kf(const float* __restrict__ kern,
                        __hip_bfloat16* __restrict__ kf)
{
    const int st = blockIdx.x;                 // 0..71
    const int sl = st / 3, tp = st - sl * 3;
    const int dh = sl >> 3, cc = sl & 7;
    const int p  = dh * 3 + tp;
    const int t    = threadIdx.x;
    const int lane = t & 63, jt2 = t >> 6;
    const int l15  = lane & 15, lk = lane >> 4;
    const int cib  = cc * 32 + lk * 8;
#pragma unroll
    for (int jj = 0; jj < 4; ++jj) {
        const int jt = jj * 4 + jt2;
        const int co = jt * 16 + l15;
        short8 v;
#pragma unroll
        for (int e = 0; e < 8; ++e)
            v[e] = f2bf(kern[(size_t)(p * 256 + cib + e) * 256 + co]);
        *(short8*)(kf + ((size_t)(st * 16 + jt) * 64 + lane) * 8) = v;
    }
}

// ---- fragment load/compute helpers -----------------------------------------
__device__ __forceinline__ void load_tap(const __hip_bfloat16* __restrict__ kf,
                                         const __hip_bfloat16* __restrict__ Xrow,
                                         int sbase, int tp, int jbase, int lane,
                                         int wr, int l15, int lk,
                                         short8 af[4], short8 bfr[4])
{
#pragma unroll
    for (int j = 0; j < 4; ++j)
        bfr[j] = *(const short8*)(kf +
            (size_t)(sbase + tp * 16 + jbase + j) * 512 + lane * 8);
#pragma unroll
    for (int i = 0; i < 4; ++i)
        af[i] = *(const short8*)&Xrow[(wr + i * 16 + l15 + tp) * PXS + lk * 8];
}

__device__ __forceinline__ void mfma_tap(f32x4 acc[4][4],
                                         const short8 af[4], const short8 bfr[4])
{
#pragma unroll
    for (int i = 0; i < 4; ++i)
#pragma unroll
        for (int j = 0; j < 4; ++j)
            acc[i][j] = __builtin_amdgcn_mfma_f32_16x16x32_bf16(
                af[i], bfr[j], acc[i][j], 0, 0, 0);
}

// ---- main: implicit-GEMM conv, f32 in / f32 out, bf16 MFMA core ------------
// One block = one (b,h) row (M=128 pixels) x 128 couts.
// v4 changes vs v3:
//  * v3 post-mortem: VGPR_Count=84 proved the scheduler SANK the ping-pong
//    loads back to just-in-time (pressure-minimizing default) — the explicit
//    ILP never existed in the emitted code, each MFMA group re-paid L2
//    latency ~12x/slice. Fix: issue ALL 3 taps' operand loads + x prefetch,
//    then __builtin_amdgcn_sched_barrier(0) — a full compile-time fence that
//    makes the sink illegal. RA must keep 3 operand sets live (~96 VGPRs);
//    waitcnt pass emits counted vmcnt(12/8/4) per tap group; x loads issued
//    last so no MFMA ever waits on them.
//  * __launch_bounds__(256,2): VGPR cap 256 (acc 64 + operands 96 + x 16 +
//    addr ~= 200). 2 waves/SIMD — explicit ILP replaces occupancy.
__global__ __launch_bounds__(256, 2) void conv_mfma(
    const float* __restrict__ x,
    const __hip_bfloat16* __restrict__ kf,
    const float* __restrict__ style,
    const float* __restrict__ demod,
    float* __restrict__ out)
{
    __shared__ __align__(16) __hip_bfloat16 Xs[2][130 * PXS];   // 20.8 KB
    __shared__ float Ss[256];
    __shared__ float Ds[128];

    const int t    = threadIdx.x;
    const int bid  = blockIdx.x;
    const int L    = ((bid & 7) << 8) | (bid >> 3);   // XCD-contiguous work id
    const int n0   = (L & 1) << 7;                    // cout tile: 0 or 128
    const int bh   = L >> 1;                          // 0..1023
    const int b    = bh >> 7, h = bh & 127;
    const int wave = t >> 6, lane = t & 63;
    const int wr   = (wave >> 1) << 6;          // wave row base
    const int wc   = (wave & 1) << 6;           // wave col base
    const int l15  = lane & 15, lk = lane >> 4;
    const int mA   = t >> 2;                    // staging row 0..63
    const int koff = (t & 3) << 3;              // staging k offset (8 elems)
    const int jbase = ((L & 1) << 3) + ((wave & 1) << 2);  // KF j-tile base

    if (t < 128) {
        ((float2*)Ss)[t] = ((const float2*)(style + b * 256))[t];
        Ds[t] = demod[b * 256 + n0 + t];
    }
    if (t < 32) {                               // halo rows, never re-written
        const __hip_bfloat16 z = __float2bfloat16(0.f);
        Xs[0][t] = z; Xs[0][129 * PXS + t] = z;
        Xs[1][t] = z; Xs[1][129 * PXS + t] = z;
    }

    f32x4 acc[4][4] = {};

    const int slo = (h == 0)   ? 8  : 0;        // valid slices are contiguous
    const int shi = (h == 127) ? 16 : 24;

    __syncthreads();                            // Ss ready for staging

    // ---- prologue: stage slice slo into buffer 0 ----
    {
        const int h2  = h + (slo >> 3) - 1;
        const int ci0 = (slo & 7) << 5;
        const size_t rowbase = (size_t)(b * 128 + h2) * 128;
        const float* ga = x + (rowbase + mA)      * 256 + ci0 + koff;
        const float* gb = x + (rowbase + mA + 64) * 256 + ci0 + koff;
        float4 xa0 = *(const float4*)ga, xa1 = *(const float4*)(ga + 4);
        float4 xb0 = *(const float4*)gb, xb1 = *(const float4*)(gb + 4);
        float4 s0  = *(const float4*)&Ss[ci0 + koff];
        float4 s1  = *(const float4*)&Ss[ci0 + koff + 4];
        short8 ma, mb;
#pragma unroll
        for (int jj = 0; jj < 4; ++jj) {
            ma[jj]     = f2bf((&xa0.x)[jj] * (&s0.x)[jj]);
            ma[jj + 4] = f2bf((&xa1.x)[jj] * (&s1.x)[jj]);
            mb[jj]     = f2bf((&xb0.x)[jj] * (&s0.x)[jj]);
            mb[jj + 4] = f2bf((&xb1.x)[jj] * (&s1.x)[jj]);
        }
        *(short8*)&Xs[0][(mA + 1)  * PXS + koff] = ma;
        *(short8*)&Xs[0][(mA + 65) * PXS + koff] = mb;
    }
    __syncthreads();                            // buf0 published

    int cur = 0;
    for (int s = slo; s < shi; ++s, cur ^= 1) {
        const int sbase = s * 48;               // KF chunk base for this slice
        const __hip_bfloat16* Xr = Xs[cur];

        // ---- issue ALL operand loads (3 tap sets) + x prefetch, then fence.
        // Load order => counted waits: mfma tap0 waits vmcnt(12) (taps 1,2 +
        // x still in flight), tap1 vmcnt(8), tap2 vmcnt(4); x waited only in
        // the modulate phase.
        short8 afA[4], bfA[4], afB[4], bfB[4], afC[4], bfC[4];
        load_tap(kf, Xr, sbase, 0, jbase, lane, wr, l15, lk, afA, bfA);
        load_tap(kf, Xr, sbase, 1, jbase, lane, wr, l15, lk, afB, bfB);
        load_tap(kf, Xr, sbase, 2, jbase, lane, wr, l15, lk, afC, bfC);

        float4 xa0, xa1, xb0, xb1;
        int nci0 = 0;
        const bool pf = (s + 1 < shi);
        if (pf) {
            const int sl = s + 1;
            const int h2 = h + (sl >> 3) - 1;
            nci0 = (sl & 7) << 5;
            const size_t rowbase = (size_t)(b * 128 + h2) * 128;
            const float* ga = x + (rowbase + mA)      * 256 + nci0 + koff;
            const float* gb = x + (rowbase + mA + 64) * 256 + nci0 + koff;
            xa0 = *(const float4*)ga; xa1 = *(const float4*)(ga + 4);
            xb0 = *(const float4*)gb; xb1 = *(const float4*)(gb + 4);
        }

        __builtin_amdgcn_sched_barrier(0);      // loads may NOT sink past here

        mfma_tap(acc, afA, bfA);                // tap0
        mfma_tap(acc, afB, bfB);                // tap1
        mfma_tap(acc, afC, bfC);                // tap2

        // ---- modulate + write next buffer (x loads landed under MFMAs) ----
        if (pf) {
            float4 s0 = *(const float4*)&Ss[nci0 + koff];
            float4 s1 = *(const float4*)&Ss[nci0 + koff + 4];
            short8 ma, mb;
#pragma unroll
            for (int jj = 0; jj < 4; ++jj) {
                ma[jj]     = f2bf((&xa0.x)[jj] * (&s0.x)[jj]);
                ma[jj + 4] = f2bf((&xa1.x)[jj] * (&s1.x)[jj]);
                mb[jj]     = f2bf((&xb0.x)[jj] * (&s0.x)[jj]);
                mb[jj + 4] = f2bf((&xb1.x)[jj] * (&s1.x)[jj]);
            }
            *(short8*)&Xs[cur ^ 1][(mA + 1)  * PXS + koff] = ma;
            *(short8*)&Xs[cur ^ 1][(mA + 65) * PXS + koff] = mb;
        }
        __syncthreads();                        // publishes buf^1, guards reuse
    }

    // ---- epilogue: demod scale + f32 store (C/D: col=lane&15, row=(lane>>4)*4+r)
    float dj[4];
#pragma unroll
    for (int j = 0; j < 4; ++j) dj[j] = Ds[wc + j * 16 + l15];
    const size_t obase = (size_t)(b * 128 + h) * 128 * 256 + n0;
#pragma unroll
    for (int i = 0; i < 4; ++i) {
#pragma unroll
        for (int j = 0; j < 4; ++j) {
            const int n = wc + j * 16 + l15;
#pragma unroll
            for (int r = 0; r < 4; ++r) {
                const int m = wr + i * 16 + lk * 4 + r;
                __builtin_nontemporal_store(acc[i][j][r] * dj[j],
                                            &out[obase + (size_t)m * 256 + n]);
            }
        }
    }
}

extern "C" void kernel_launch(void* const* d_in, const int* in_sizes, int n_in,
                              void* d_out, int out_size, void* d_ws, size_t ws_size,
                              hipStream_t stream)
{
    const float* x     = (const float*)d_in[0];
    const float* style = (const float*)d_in[1];
    const float* kern  = (const float*)d_in[2];
    float* out = (float*)d_out;

    char*  ws    = (char*)d_ws;
    float* demod = (float*)ws;                           // 2048 f32   (8 KB)
    float* K2    = (float*)(ws + 8192);                  // 65536 f32  (256 KB)
    __hip_bfloat16* kT = (__hip_bfloat16*)(ws + 270336); // 589824 bf16 (1.18 MB)

    prep_k2   <<<256, 256, 0, stream>>>(kern, K2);
    prep_demod<<<8,   256, 0, stream>>>(style, K2, demod);
    prep_kf   <<<72,  256, 0, stream>>>(kern, kT);
    conv_mfma <<<2048, 256, 0, stream>>>(x, kT, style, demod, out);
}